// Round 13
// baseline (465.537 us; speedup 1.0000x reference)
//
#include <hip/hip_runtime.h>
#include <hip/hip_bf16.h>
#include <math.h>

#define TT 32
#define NN 2048
#define FF 64

typedef float f32x4 __attribute__((ext_vector_type(4)));
typedef __bf16 bf16x8 __attribute__((ext_vector_type(8)));
typedef unsigned short u16x8 __attribute__((ext_vector_type(8)));

__device__ __forceinline__ unsigned short f2bf(float f) {
    __bf16 h = (__bf16)f;
    return __builtin_bit_cast(unsigned short, h);
}

// ---------------------------------------------------------------------------
// K_A: per-timestep scores (fp64) + top-64 (desc, min-index tie-break) +
// z^T[t][j][f] = X[idx_j][f] * tanh(val_j).  grid = T, 256 threads.
// (R10-proven version)
// ---------------------------------------------------------------------------
__global__ __launch_bounds__(256) void topk_kernel(
    const float* __restrict__ X, const float* __restrict__ mask,
    const float* __restrict__ scorer, float* __restrict__ zt)
{
    const int t = blockIdx.x, tid = threadIdx.x;
    __shared__ double svals[64];
    __shared__ int    sidx[64];
    __shared__ double swv[4];
    __shared__ int    swi[4];

    float sc[64];
#pragma unroll
    for (int f = 0; f < 64; f += 4) {
        float4 v = *(const float4*)(scorer + f);
        sc[f] = v.x; sc[f+1] = v.y; sc[f+2] = v.z; sc[f+3] = v.w;
    }
    double nrm = 0.0;
#pragma unroll
    for (int f = 0; f < 64; ++f) nrm += (double)sc[f] * (double)sc[f];
    const double inv = 1.0 / sqrt(nrm);

    const float* Xt = X + (size_t)t * NN * FF;
    double ls[8];
#pragma unroll
    for (int e = 0; e < 8; ++e) {
        const int n = e * 256 + tid;
        const float* xr = Xt + (size_t)n * FF;
        double s = 0.0;
#pragma unroll
        for (int f = 0; f < 64; f += 4) {
            float4 v = *(const float4*)(xr + f);
            s += (double)v.x * (double)sc[f]   + (double)v.y * (double)sc[f+1]
               + (double)v.z * (double)sc[f+2] + (double)v.w * (double)sc[f+3];
        }
        ls[e] = s * inv + (double)mask[t * NN + n];
    }

    const int lane = tid & 63, w = tid >> 6;
    for (int r = 0; r < 64; ++r) {
        double bv = ls[0]; int bi = tid;
#pragma unroll
        for (int e = 1; e < 8; ++e) {
            const int n = e * 256 + tid;
            if (ls[e] > bv) { bv = ls[e]; bi = n; }
        }
#pragma unroll
        for (int off = 1; off < 64; off <<= 1) {
            double ov = __shfl_xor(bv, off);
            int    oi = __shfl_xor(bi, off);
            if (ov > bv || (ov == bv && oi < bi)) { bv = ov; bi = oi; }
        }
        if (lane == 0) { swv[w] = bv; swi[w] = bi; }
        __syncthreads();
        if (tid == 0) {
            double fv = swv[0]; int fi = swi[0];
#pragma unroll
            for (int q = 1; q < 4; ++q)
                if (swv[q] > fv || (swv[q] == fv && swi[q] < fi)) { fv = swv[q]; fi = swi[q]; }
            svals[r] = fv; sidx[r] = fi;
        }
        __syncthreads();
        const int win = sidx[r];
#pragma unroll
        for (int e = 0; e < 8; ++e)
            if (win == e * 256 + tid) ls[e] = -INFINITY;
    }
    __syncthreads();

    const int j = tid >> 2, fg = tid & 3;
    const float th  = tanhf((float)svals[j]);
    const int  idx  = sidx[j];
    const float* xr = Xt + (size_t)idx * FF + fg * 16;
    float* zr = zt + (size_t)t * 4096 + j * 64 + fg * 16;
#pragma unroll
    for (int f = 0; f < 16; f += 4) {
        float4 v = *(const float4*)(xr + f);
        *(float4*)(zr + f) = make_float4(v.x * th, v.y * th, v.z * th, v.w * th);
    }
}

// ---------------------------------------------------------------------------
// K_W: Wz[m][t][i][j] = b_m[i][j] + sum_f W_m[i][f] * z[f][j]
// ---------------------------------------------------------------------------
__global__ __launch_bounds__(256) void wz_kernel(
    const float* __restrict__ zt,
    const float* __restrict__ Wu, const float* __restrict__ bu,
    const float* __restrict__ Wr, const float* __restrict__ br,
    const float* __restrict__ Wh, const float* __restrict__ bh,
    float* __restrict__ Wz)
{
    const int m = blockIdx.x, t = blockIdx.y, tid = threadIdx.x;
    const float* W = (m == 0) ? Wu : (m == 1) ? Wr : Wh;
    const float* b = (m == 0) ? bu : (m == 1) ? br : bh;
    const int j = tid & 63, i0 = (tid >> 6) << 4;

    float zr[64];
    const float* zrow = zt + (size_t)t * 4096 + j * 64;
#pragma unroll
    for (int f = 0; f < 64; f += 4) {
        float4 v = *(const float4*)(zrow + f);
        zr[f] = v.x; zr[f+1] = v.y; zr[f+2] = v.z; zr[f+3] = v.w;
    }
    float* o = Wz + ((size_t)m * TT + t) * 4096;
    for (int i = i0; i < i0 + 16; ++i) {
        float acc = b[i * 64 + j];
#pragma unroll
        for (int f = 0; f < 64; ++f) acc += W[i * 64 + f] * zr[f];
        o[i * 64 + j] = acc;
    }
}

// ---------------------------------------------------------------------------
// K_B: column-separable GRU chain, one Q-column per block (R10 4-wave ver).
// ---------------------------------------------------------------------------
__global__ __launch_bounds__(256) void qchain_kernel(
    const float* __restrict__ Q0,
    const float* __restrict__ Uu, const float* __restrict__ Ur, const float* __restrict__ Uh,
    const float* __restrict__ Wz, float* __restrict__ Qseq)
{
    const int j = blockIdx.x, tid = threadIdx.x;
    const int w = tid >> 6, l = tid & 63;
    const int i = (w << 4) + (l & 15);
    const int fq = l >> 4, fb = fq << 4;

    float uu[16], ur[16], uh[16];
#pragma unroll
    for (int e = 0; e < 16; e += 4) {
        float4 a = *(const float4*)(Uu + i * 64 + fb + e);
        uu[e] = a.x; uu[e+1] = a.y; uu[e+2] = a.z; uu[e+3] = a.w;
        float4 c = *(const float4*)(Ur + i * 64 + fb + e);
        ur[e] = c.x; ur[e+1] = c.y; ur[e+2] = c.z; ur[e+3] = c.w;
        float4 d = *(const float4*)(Uh + i * 64 + fb + e);
        uh[e] = d.x; uh[e+1] = d.y; uh[e+2] = d.z; uh[e+3] = d.w;
    }
    __shared__ __align__(16) float q[64];
    __shared__ __align__(16) float rr[64];
    if (tid < 64) q[tid] = Q0[tid * 64 + j];
    __syncthreads();

    const float* WzU = Wz;
    const float* WzR = Wz + (size_t)TT * 4096;
    const float* WzH = Wz + (size_t)2 * TT * 4096;

    for (int t = 0; t < TT; ++t) {
        float q16[16];
#pragma unroll
        for (int e = 0; e < 16; e += 4) {
            f32x4 v = *(const f32x4*)(&q[fb + e]);
            q16[e] = v[0]; q16[e+1] = v[1]; q16[e+2] = v[2]; q16[e+3] = v[3];
        }
        float su = 0.f, sr = 0.f;
#pragma unroll
        for (int e = 0; e < 16; ++e) { su += uu[e] * q16[e]; sr += ur[e] * q16[e]; }
        su += __shfl_xor(su, 16); su += __shfl_xor(su, 32);
        sr += __shfl_xor(sr, 16); sr += __shfl_xor(sr, 32);
        const int off = t * 4096 + i * 64 + j;
        const float u_ = 1.f / (1.f + expf(-(su + WzU[off])));
        const float r_ = 1.f / (1.f + expf(-(sr + WzR[off])));
        if (fq == 0) rr[i] = r_;
        __syncthreads();
        float sh = 0.f;
#pragma unroll
        for (int e = 0; e < 16; e += 4) {
            f32x4 v = *(const f32x4*)(&rr[fb + e]);
            sh += uh[e]   * (v[0] * q16[e]);
            sh += uh[e+1] * (v[1] * q16[e+1]);
            sh += uh[e+2] * (v[2] * q16[e+2]);
            sh += uh[e+3] * (v[3] * q16[e+3]);
        }
        sh += __shfl_xor(sh, 16); sh += __shfl_xor(sh, 32);
        float hv = sh + WzH[off];
        hv = hv > 0.f ? hv : 0.f;
        const float qi = q[i];
        const float qn = (1.f - u_) * qi + u_ * hv;
        __syncthreads();
        if (fq == 0) {
            q[i] = qn;
            Qseq[(size_t)t * 4096 + i * 64 + j] = qn;
        }
        __syncthreads();
    }
}

// ---------------------------------------------------------------------------
// K_C: Ytr[t][j][n] = bf16( sum_f X[t][n][f] * Qseq[t][f][j] )
// LDS transpose -> 16B contiguous global stores.
// ---------------------------------------------------------------------------
__global__ __launch_bounds__(256) void y_kernel(
    const float* __restrict__ X, const float* __restrict__ Qseq,
    unsigned short* __restrict__ Ytr)
{
    const int t = blockIdx.y, tid = threadIdx.x;
    const int n0 = blockIdx.x * 256;
    const int n = n0 + tid;
    __shared__ __align__(16) float Qs[4096];
    __shared__ __align__(16) unsigned short Ys[64][264];  // [j][local n], padded
    for (int c = tid; c < 4096; c += 256) Qs[c] = Qseq[(size_t)t * 4096 + c];
    __syncthreads();

    const float* xr = X + ((size_t)t * NN + n) * FF;
    float y[64];
#pragma unroll
    for (int jj = 0; jj < 64; ++jj) y[jj] = 0.f;
    for (int f4 = 0; f4 < 64; f4 += 4) {
        float4 xv = *(const float4*)(xr + f4);
        float xa[4] = {xv.x, xv.y, xv.z, xv.w};
#pragma unroll
        for (int ff = 0; ff < 4; ++ff) {
            const float xf = xa[ff];
            const float* qr = &Qs[(f4 + ff) << 6];
#pragma unroll
            for (int jj = 0; jj < 64; jj += 4) {
                f32x4 qv = *(const f32x4*)(qr + jj);
                y[jj]   += xf * qv[0];
                y[jj+1] += xf * qv[1];
                y[jj+2] += xf * qv[2];
                y[jj+3] += xf * qv[3];
            }
        }
    }
#pragma unroll
    for (int jj = 0; jj < 64; ++jj) Ys[jj][tid] = f2bf(y[jj]);
    __syncthreads();

    const int j = tid >> 2, nc = (tid & 3) << 6;
    unsigned short* yo = Ytr + (size_t)t * FF * NN + (size_t)j * NN + n0 + nc;
#pragma unroll
    for (int c = 0; c < 8; ++c)
        *(u16x8*)(yo + c * 8) = *(const u16x8*)(&Ys[j][nc + c * 8]);
}

// ---------------------------------------------------------------------------
// K_D: out[t] = relu(A[t] @ Y[t]).  R10 gemm (measured 112us @ 4.6 TB/s).
// ---------------------------------------------------------------------------
__global__ __launch_bounds__(256, 4) void gemm_kernel(
    const float* __restrict__ A, const unsigned short* __restrict__ Ytr,
    float* __restrict__ out)
{
    __shared__ __align__(16) unsigned char Abuf[16384];  // f32 [64 r][256B]
    __shared__ __align__(16) unsigned char Bbuf[8192];   // bf16 [64 j][128B]
    const int tid = threadIdx.x;
    const int bid = blockIdx.x;
    const int xcd = bid & 7, li = bid >> 3;          // 8 XCDs x 128 blocks
    const int t = (xcd << 2) + (li >> 5);            // 4 timesteps per XCD
    const int m0 = (li & 31) * 64;
    const int lane = tid & 63, w = tid >> 6;
    const int lr = lane & 15, lq = lane >> 4;

    const float* Ap = A + (size_t)t * NN * NN + (size_t)m0 * NN;
    const unsigned short* Yp = Ytr + (size_t)t * FF * NN;

    f32x4 acc[4];
#pragma unroll
    for (int nt = 0; nt < 4; ++nt) acc[nt] = (f32x4){0.f, 0.f, 0.f, 0.f};

    for (int kt = 0; kt < 32; ++kt) {
        const int kk = kt << 6;
#pragma unroll
        for (int q = 0; q < 4; ++q) {
            const int row = (w << 4) + (q << 2) + lq;
            const float* g = Ap + (size_t)row * NN + kk + ((lr ^ (row & 7)) << 2);
            __builtin_amdgcn_global_load_lds(
                (const __attribute__((address_space(1))) void*)g,
                (__attribute__((address_space(3))) void*)
                    (&Abuf[((w << 4) + (q << 2)) << 8]), 16, 0, 0);
        }
#pragma unroll
        for (int q = 0; q < 2; ++q) {
            const int j = (w << 4) + (q << 3) + (lane >> 3);
            const unsigned short* g = Yp + (size_t)j * NN + kk
                                    + (((lane & 7) ^ (j & 7)) << 3);
            __builtin_amdgcn_global_load_lds(
                (const __attribute__((address_space(1))) void*)g,
                (__attribute__((address_space(3))) void*)
                    (&Bbuf[((w << 4) + (q << 3)) << 7]), 16, 0, 0);
        }
        __syncthreads();
#pragma unroll
        for (int ks = 0; ks < 2; ++ks) {
            const int r = (w << 4) + lr;
            const int c0 = ((ks << 3) + (lq << 1)) ^ (lr & 7);
            const int c1 = ((ks << 3) + (lq << 1) + 1) ^ (lr & 7);
            const f32x4 a0 = *(const f32x4*)(&Abuf[(r << 8) + (c0 << 4)]);
            const f32x4 a1 = *(const f32x4*)(&Abuf[(r << 8) + (c1 << 4)]);
            bf16x8 af;
            af[0] = (__bf16)a0[0]; af[1] = (__bf16)a0[1];
            af[2] = (__bf16)a0[2]; af[3] = (__bf16)a0[3];
            af[4] = (__bf16)a1[0]; af[5] = (__bf16)a1[1];
            af[6] = (__bf16)a1[2]; af[7] = (__bf16)a1[3];
#pragma unroll
            for (int nt = 0; nt < 4; ++nt) {
                const int j = (nt << 4) + lr;
                const int x = ((ks << 2) + lq) ^ (j & 7);
                const bf16x8 bf = *(const bf16x8*)(&Bbuf[(j << 7) + (x << 4)]);
                acc[nt] = __builtin_amdgcn_mfma_f32_16x16x32_bf16(
                    af, bf, acc[nt], 0, 0, 0);
            }
        }
        __syncthreads();
    }

#pragma unroll
    for (int nt = 0; nt < 4; ++nt) {
        const int row0 = m0 + (w << 4) + (lq << 2);
        const int col = (nt << 4) + lr;
#pragma unroll
        for (int rg = 0; rg < 4; ++rg) {
            const float v = acc[nt][rg];
            out[((size_t)t * NN + (row0 + rg)) * FF + col] = v > 0.f ? v : 0.f;
        }
    }
}

// ---------------------------------------------------------------------------
// MEASUREMENT ROUND: R10-proven pipeline, but the four SMALL kernels are
// launched TWICE each (all idempotent). smalls_cost = total - 312us.
// ---------------------------------------------------------------------------
extern "C" void kernel_launch(void* const* d_in, const int* in_sizes, int n_in,
                              void* d_out, int out_size, void* d_ws, size_t ws_size,
                              hipStream_t stream) {
    const float* A      = (const float*)d_in[0];
    const float* X      = (const float*)d_in[1];
    const float* mask   = (const float*)d_in[2];
    const float* Q0     = (const float*)d_in[3];
    const float* scorer = (const float*)d_in[4];
    const float* Wu     = (const float*)d_in[5];
    const float* Uu     = (const float*)d_in[6];
    const float* bu     = (const float*)d_in[7];
    const float* Wr     = (const float*)d_in[8];
    const float* Ur     = (const float*)d_in[9];
    const float* br     = (const float*)d_in[10];
    const float* Wh     = (const float*)d_in[11];
    const float* Uh     = (const float*)d_in[12];
    const float* bh     = (const float*)d_in[13];
    float* out = (float*)d_out;

    float* ws   = (float*)d_ws;
    float* zt   = ws;              // [T][64][64]
    float* Wz   = ws + 131072;     // [3][T][64][64]
    float* Qseq = ws + 524288;     // [T][64][64]
    unsigned short* Ytr = (unsigned short*)(ws + 655360);  // [T][64][2048] bf16

    topk_kernel<<<TT, 256, 0, stream>>>(X, mask, scorer, zt);
    topk_kernel<<<TT, 256, 0, stream>>>(X, mask, scorer, zt);
    wz_kernel<<<dim3(3, TT), 256, 0, stream>>>(zt, Wu, bu, Wr, br, Wh, bh, Wz);
    wz_kernel<<<dim3(3, TT), 256, 0, stream>>>(zt, Wu, bu, Wr, br, Wh, bh, Wz);
    qchain_kernel<<<FF, 256, 0, stream>>>(Q0, Uu, Ur, Uh, Wz, Qseq);
    qchain_kernel<<<FF, 256, 0, stream>>>(Q0, Uu, Ur, Uh, Wz, Qseq);
    y_kernel<<<dim3(NN / 256, TT), 256, 0, stream>>>(X, Qseq, Ytr);
    y_kernel<<<dim3(NN / 256, TT), 256, 0, stream>>>(X, Qseq, Ytr);
    gemm_kernel<<<1024, 256, 0, stream>>>(A, Ytr, out);
}

// Round 14
// 302.981 us; speedup vs baseline: 1.5365x; 1.5365x over previous
//
#include <hip/hip_runtime.h>
#include <hip/hip_bf16.h>
#include <math.h>

#define TT 32
#define NN 2048
#define FF 64

typedef float f32x4 __attribute__((ext_vector_type(4)));
typedef __bf16 bf16x8 __attribute__((ext_vector_type(8)));
typedef unsigned short u16x8 __attribute__((ext_vector_type(8)));

__device__ __forceinline__ unsigned short f2bf(float f) {
    __bf16 h = (__bf16)f;
    return __builtin_bit_cast(unsigned short, h);
}

// ---------------------------------------------------------------------------
// K_A (fused topk v3 + wz): fp64 scores -> per-wave serial top-64 (barrier-
// free butterfly extraction, 512 elems/wave) -> 256-candidate bitonic merge
// (desc, idx-asc; R12-verified comparator) -> Wz = W_m @ z + b_m.
// grid = T blocks, 256 threads.
// ---------------------------------------------------------------------------
__global__ __launch_bounds__(256) void topkwz_kernel(
    const float* __restrict__ X, const float* __restrict__ mask,
    const float* __restrict__ scorer,
    const float* __restrict__ Wu, const float* __restrict__ bu,
    const float* __restrict__ Wr, const float* __restrict__ br,
    const float* __restrict__ Wh, const float* __restrict__ bh,
    float* __restrict__ Wz)
{
    const int t = blockIdx.x, tid = threadIdx.x;
    const int lane = tid & 63, w = tid >> 6;
    __shared__ double sk[256];
    __shared__ int    si[256];

    // ---- fp64 scores; wave w owns n in [w*512, w*512+512), lane: 8 elems ----
    float sc[64];
#pragma unroll
    for (int f = 0; f < 64; f += 4) {
        float4 v = *(const float4*)(scorer + f);
        sc[f] = v.x; sc[f+1] = v.y; sc[f+2] = v.z; sc[f+3] = v.w;
    }
    double nrm = 0.0;
#pragma unroll
    for (int f = 0; f < 64; ++f) nrm += (double)sc[f] * (double)sc[f];
    const double inv = 1.0 / sqrt(nrm);

    const float* Xt = X + (size_t)t * NN * FF;
    double ls[8];
#pragma unroll
    for (int e = 0; e < 8; ++e) {
        const int n = (w << 9) + (e << 6) + lane;
        const float* xr = Xt + (size_t)n * FF;
        double s = 0.0;
#pragma unroll
        for (int f = 0; f < 64; f += 4) {
            float4 v = *(const float4*)(xr + f);
            s += (double)v.x * (double)sc[f]   + (double)v.y * (double)sc[f+1]
               + (double)v.z * (double)sc[f+2] + (double)v.w * (double)sc[f+3];
        }
        ls[e] = s * inv + (double)mask[t * NN + n];
    }

    // ---- per-wave serial top-64 extraction (no block barriers) ----
    for (int r = 0; r < 64; ++r) {
        double bv = ls[0];
        int be = 0;
#pragma unroll
        for (int e = 1; e < 8; ++e)
            if (ls[e] > bv) { bv = ls[e]; be = e; }
        int bi = (w << 9) + (be << 6) + lane;
#pragma unroll
        for (int off = 1; off < 64; off <<= 1) {
            double ov = __shfl_xor(bv, off);
            int    oi = __shfl_xor(bi, off);
            if (ov > bv || (ov == bv && oi < bi)) { bv = ov; bi = oi; }
        }
        if (lane == 0) { sk[(w << 6) + r] = bv; si[(w << 6) + r] = bi; }
        if ((bi & 63) == lane) ls[(bi >> 6) & 7] = -INFINITY;
    }
    __syncthreads();

    // ---- bitonic merge of 256 candidates, best-first (desc, idx asc) ----
    for (int k = 2; k <= 256; k <<= 1) {
        for (int jj = k >> 1; jj > 0; jj >>= 1) {
            const int i = tid, l = i ^ jj;
            if (l > i && i < 256) {
                const double a = sk[i], b2 = sk[l];
                const int ai = si[i], bi2 = si[l];
                const bool ib = (a > b2) || (a == b2 && ai < bi2);
                const bool keep = ((i & k) == 0) ? ib : !ib;
                if (!keep) {
                    sk[i] = b2; sk[l] = a;
                    si[i] = bi2; si[l] = ai;
                }
            }
            __syncthreads();
        }
    }

    // ---- Wz phase: thread -> col j2 = tid&63, rows i0..i0+15 ----
    const int j2 = tid & 63, i0 = (tid >> 6) << 4;
    const float th = tanhf((float)sk[j2]);
    const int  idx = si[j2];
    float zr[64];
    const float* xr = Xt + (size_t)idx * FF;
#pragma unroll
    for (int f = 0; f < 64; f += 4) {
        float4 v = *(const float4*)(xr + f);
        zr[f] = v.x * th; zr[f+1] = v.y * th;
        zr[f+2] = v.z * th; zr[f+3] = v.w * th;
    }
#pragma unroll
    for (int m = 0; m < 3; ++m) {
        const float* W = (m == 0) ? Wu : (m == 1) ? Wr : Wh;
        const float* b = (m == 0) ? bu : (m == 1) ? br : bh;
        float* o = Wz + ((size_t)m * TT + t) * 4096;
        for (int i = i0; i < i0 + 16; ++i) {
            float acc = b[i * 64 + j2];
#pragma unroll
            for (int f = 0; f < 64; ++f) acc += W[i * 64 + f] * zr[f];
            o[i * 64 + j2] = acc;
        }
    }
}

// ---------------------------------------------------------------------------
// K_B: column-separable GRU chain, one Q-column per block (R10 4-wave ver).
// ---------------------------------------------------------------------------
__global__ __launch_bounds__(256) void qchain_kernel(
    const float* __restrict__ Q0,
    const float* __restrict__ Uu, const float* __restrict__ Ur, const float* __restrict__ Uh,
    const float* __restrict__ Wz, float* __restrict__ Qseq)
{
    const int j = blockIdx.x, tid = threadIdx.x;
    const int w = tid >> 6, l = tid & 63;
    const int i = (w << 4) + (l & 15);
    const int fq = l >> 4, fb = fq << 4;

    float uu[16], ur[16], uh[16];
#pragma unroll
    for (int e = 0; e < 16; e += 4) {
        float4 a = *(const float4*)(Uu + i * 64 + fb + e);
        uu[e] = a.x; uu[e+1] = a.y; uu[e+2] = a.z; uu[e+3] = a.w;
        float4 c = *(const float4*)(Ur + i * 64 + fb + e);
        ur[e] = c.x; ur[e+1] = c.y; ur[e+2] = c.z; ur[e+3] = c.w;
        float4 d = *(const float4*)(Uh + i * 64 + fb + e);
        uh[e] = d.x; uh[e+1] = d.y; uh[e+2] = d.z; uh[e+3] = d.w;
    }
    __shared__ __align__(16) float q[64];
    __shared__ __align__(16) float rr[64];
    if (tid < 64) q[tid] = Q0[tid * 64 + j];
    __syncthreads();

    const float* WzU = Wz;
    const float* WzR = Wz + (size_t)TT * 4096;
    const float* WzH = Wz + (size_t)2 * TT * 4096;

    for (int t = 0; t < TT; ++t) {
        float q16[16];
#pragma unroll
        for (int e = 0; e < 16; e += 4) {
            f32x4 v = *(const f32x4*)(&q[fb + e]);
            q16[e] = v[0]; q16[e+1] = v[1]; q16[e+2] = v[2]; q16[e+3] = v[3];
        }
        float su = 0.f, sr = 0.f;
#pragma unroll
        for (int e = 0; e < 16; ++e) { su += uu[e] * q16[e]; sr += ur[e] * q16[e]; }
        su += __shfl_xor(su, 16); su += __shfl_xor(su, 32);
        sr += __shfl_xor(sr, 16); sr += __shfl_xor(sr, 32);
        const int off = t * 4096 + i * 64 + j;
        const float u_ = 1.f / (1.f + expf(-(su + WzU[off])));
        const float r_ = 1.f / (1.f + expf(-(sr + WzR[off])));
        if (fq == 0) rr[i] = r_;
        __syncthreads();
        float sh = 0.f;
#pragma unroll
        for (int e = 0; e < 16; e += 4) {
            f32x4 v = *(const f32x4*)(&rr[fb + e]);
            sh += uh[e]   * (v[0] * q16[e]);
            sh += uh[e+1] * (v[1] * q16[e+1]);
            sh += uh[e+2] * (v[2] * q16[e+2]);
            sh += uh[e+3] * (v[3] * q16[e+3]);
        }
        sh += __shfl_xor(sh, 16); sh += __shfl_xor(sh, 32);
        float hv = sh + WzH[off];
        hv = hv > 0.f ? hv : 0.f;
        const float qi = q[i];
        const float qn = (1.f - u_) * qi + u_ * hv;
        __syncthreads();
        if (fq == 0) {
            q[i] = qn;
            Qseq[(size_t)t * 4096 + i * 64 + j] = qn;
        }
        __syncthreads();
    }
}

// ---------------------------------------------------------------------------
// K_C: Ytr[t][j][n] = bf16( sum_f X[t][n][f] * Qseq[t][f][j] )
// LDS transpose -> 16B contiguous global stores.
// ---------------------------------------------------------------------------
__global__ __launch_bounds__(256) void y_kernel(
    const float* __restrict__ X, const float* __restrict__ Qseq,
    unsigned short* __restrict__ Ytr)
{
    const int t = blockIdx.y, tid = threadIdx.x;
    const int n0 = blockIdx.x * 256;
    const int n = n0 + tid;
    __shared__ __align__(16) float Qs[4096];
    __shared__ __align__(16) unsigned short Ys[64][264];  // [j][local n], padded
    for (int c = tid; c < 4096; c += 256) Qs[c] = Qseq[(size_t)t * 4096 + c];
    __syncthreads();

    const float* xr = X + ((size_t)t * NN + n) * FF;
    float y[64];
#pragma unroll
    for (int jj = 0; jj < 64; ++jj) y[jj] = 0.f;
    for (int f4 = 0; f4 < 64; f4 += 4) {
        float4 xv = *(const float4*)(xr + f4);
        float xa[4] = {xv.x, xv.y, xv.z, xv.w};
#pragma unroll
        for (int ff = 0; ff < 4; ++ff) {
            const float xf = xa[ff];
            const float* qr = &Qs[(f4 + ff) << 6];
#pragma unroll
            for (int jj = 0; jj < 64; jj += 4) {
                f32x4 qv = *(const f32x4*)(qr + jj);
                y[jj]   += xf * qv[0];
                y[jj+1] += xf * qv[1];
                y[jj+2] += xf * qv[2];
                y[jj+3] += xf * qv[3];
            }
        }
    }
#pragma unroll
    for (int jj = 0; jj < 64; ++jj) Ys[jj][tid] = f2bf(y[jj]);
    __syncthreads();

    const int j = tid >> 2, nc = (tid & 3) << 6;
    unsigned short* yo = Ytr + (size_t)t * FF * NN + (size_t)j * NN + n0 + nc;
#pragma unroll
    for (int c = 0; c < 8; ++c)
        *(u16x8*)(yo + c * 8) = *(const u16x8*)(&Ys[j][nc + c * 8]);
}

// ---------------------------------------------------------------------------
// K_D: out[t] = relu(A[t] @ Y[t]).  R10 gemm (measured 112us @ 4.6 TB/s).
// ---------------------------------------------------------------------------
__global__ __launch_bounds__(256, 4) void gemm_kernel(
    const float* __restrict__ A, const unsigned short* __restrict__ Ytr,
    float* __restrict__ out)
{
    __shared__ __align__(16) unsigned char Abuf[16384];  // f32 [64 r][256B]
    __shared__ __align__(16) unsigned char Bbuf[8192];   // bf16 [64 j][128B]
    const int tid = threadIdx.x;
    const int bid = blockIdx.x;
    const int xcd = bid & 7, li = bid >> 3;          // 8 XCDs x 128 blocks
    const int t = (xcd << 2) + (li >> 5);            // 4 timesteps per XCD
    const int m0 = (li & 31) * 64;
    const int lane = tid & 63, w = tid >> 6;
    const int lr = lane & 15, lq = lane >> 4;

    const float* Ap = A + (size_t)t * NN * NN + (size_t)m0 * NN;
    const unsigned short* Yp = Ytr + (size_t)t * FF * NN;

    f32x4 acc[4];
#pragma unroll
    for (int nt = 0; nt < 4; ++nt) acc[nt] = (f32x4){0.f, 0.f, 0.f, 0.f};

    for (int kt = 0; kt < 32; ++kt) {
        const int kk = kt << 6;
#pragma unroll
        for (int q = 0; q < 4; ++q) {
            const int row = (w << 4) + (q << 2) + lq;
            const float* g = Ap + (size_t)row * NN + kk + ((lr ^ (row & 7)) << 2);
            __builtin_amdgcn_global_load_lds(
                (const __attribute__((address_space(1))) void*)g,
                (__attribute__((address_space(3))) void*)
                    (&Abuf[((w << 4) + (q << 2)) << 8]), 16, 0, 0);
        }
#pragma unroll
        for (int q = 0; q < 2; ++q) {
            const int j = (w << 4) + (q << 3) + (lane >> 3);
            const unsigned short* g = Yp + (size_t)j * NN + kk
                                    + (((lane & 7) ^ (j & 7)) << 3);
            __builtin_amdgcn_global_load_lds(
                (const __attribute__((address_space(1))) void*)g,
                (__attribute__((address_space(3))) void*)
                    (&Bbuf[((w << 4) + (q << 3)) << 7]), 16, 0, 0);
        }
        __syncthreads();
#pragma unroll
        for (int ks = 0; ks < 2; ++ks) {
            const int r = (w << 4) + lr;
            const int c0 = ((ks << 3) + (lq << 1)) ^ (lr & 7);
            const int c1 = ((ks << 3) + (lq << 1) + 1) ^ (lr & 7);
            const f32x4 a0 = *(const f32x4*)(&Abuf[(r << 8) + (c0 << 4)]);
            const f32x4 a1 = *(const f32x4*)(&Abuf[(r << 8) + (c1 << 4)]);
            bf16x8 af;
            af[0] = (__bf16)a0[0]; af[1] = (__bf16)a0[1];
            af[2] = (__bf16)a0[2]; af[3] = (__bf16)a0[3];
            af[4] = (__bf16)a1[0]; af[5] = (__bf16)a1[1];
            af[6] = (__bf16)a1[2]; af[7] = (__bf16)a1[3];
#pragma unroll
            for (int nt = 0; nt < 4; ++nt) {
                const int j = (nt << 4) + lr;
                const int x = ((ks << 2) + lq) ^ (j & 7);
                const bf16x8 bf = *(const bf16x8*)(&Bbuf[(j << 7) + (x << 4)]);
                acc[nt] = __builtin_amdgcn_mfma_f32_16x16x32_bf16(
                    af, bf, acc[nt], 0, 0, 0);
            }
        }
        __syncthreads();
    }

#pragma unroll
    for (int nt = 0; nt < 4; ++nt) {
        const int row0 = m0 + (w << 4) + (lq << 2);
        const int col = (nt << 4) + lr;
#pragma unroll
        for (int rg = 0; rg < 4; ++rg) {
            const float v = acc[nt][rg];
            out[((size_t)t * NN + (row0 + rg)) * FF + col] = v > 0.f ? v : 0.f;
        }
    }
}

// ---------------------------------------------------------------------------
extern "C" void kernel_launch(void* const* d_in, const int* in_sizes, int n_in,
                              void* d_out, int out_size, void* d_ws, size_t ws_size,
                              hipStream_t stream) {
    const float* A      = (const float*)d_in[0];
    const float* X      = (const float*)d_in[1];
    const float* mask   = (const float*)d_in[2];
    const float* Q0     = (const float*)d_in[3];
    const float* scorer = (const float*)d_in[4];
    const float* Wu     = (const float*)d_in[5];
    const float* Uu     = (const float*)d_in[6];
    const float* bu     = (const float*)d_in[7];
    const float* Wr     = (const float*)d_in[8];
    const float* Ur     = (const float*)d_in[9];
    const float* br     = (const float*)d_in[10];
    const float* Wh     = (const float*)d_in[11];
    const float* Uh     = (const float*)d_in[12];
    const float* bh     = (const float*)d_in[13];
    float* out = (float*)d_out;

    float* ws   = (float*)d_ws;
    float* Wz   = ws + 131072;     // [3][T][64][64]
    float* Qseq = ws + 524288;     // [T][64][64]
    unsigned short* Ytr = (unsigned short*)(ws + 655360);  // [T][64][2048] bf16

    topkwz_kernel<<<TT, 256, 0, stream>>>(X, mask, scorer,
                                          Wu, bu, Wr, br, Wh, bh, Wz);
    qchain_kernel<<<FF, 256, 0, stream>>>(Q0, Uu, Ur, Uh, Wz, Qseq);
    y_kernel<<<dim3(NN / 256, TT), 256, 0, stream>>>(X, Qseq, Ytr);
    gemm_kernel<<<1024, 256, 0, stream>>>(A, Ytr, out);
}

// Round 16
// 299.537 us; speedup vs baseline: 1.5542x; 1.0115x over previous
//
#include <hip/hip_runtime.h>
#include <hip/hip_bf16.h>
#include <math.h>

#define TT 32
#define NN 2048
#define FF 64

typedef float f32x4 __attribute__((ext_vector_type(4)));
typedef __bf16 bf16x8 __attribute__((ext_vector_type(8)));
typedef unsigned short u16x8 __attribute__((ext_vector_type(8)));

__device__ __forceinline__ unsigned short f2bf(float f) {
    __bf16 h = (__bf16)f;
    return __builtin_bit_cast(unsigned short, h);
}

// ---------------------------------------------------------------------------
// K_A topk v4: grid = T blocks x 1024 threads (16 waves).
// fp64 scores (2 elems/thread) -> per-wave top-64-of-128 (explicit 2-way
// select, no dynamic reg indexing) -> 1024-candidate bitonic (desc, idx-asc;
// R12/R14-verified comparator) -> write (idx, tanh(val)) only.
// ---------------------------------------------------------------------------
__global__ __launch_bounds__(1024) void topk_kernel(
    const float* __restrict__ X, const float* __restrict__ mask,
    const float* __restrict__ scorer,
    int* __restrict__ tkidx, float* __restrict__ tkval)
{
    const int t = blockIdx.x, tid = threadIdx.x;
    const int lane = tid & 63, w = tid >> 6;   // 16 waves
    __shared__ float  scf[64];
    __shared__ double sk[1024];
    __shared__ int    si[1024];

    if (tid < 64) scf[tid] = scorer[tid];
    __syncthreads();

    double nrm = 0.0;
#pragma unroll
    for (int f = 0; f < 64; ++f) nrm += (double)scf[f] * (double)scf[f];
    const double inv = 1.0 / sqrt(nrm);

    const float* Xt = X + (size_t)t * NN * FF;
    double ls0, ls1;
    {
        const int n0 = tid, n1 = 1024 + tid;
        const float* xr0 = Xt + (size_t)n0 * FF;
        const float* xr1 = Xt + (size_t)n1 * FF;
        double s0 = 0.0, s1 = 0.0;
#pragma unroll
        for (int f = 0; f < 64; f += 4) {
            float4 v0 = *(const float4*)(xr0 + f);
            float4 v1 = *(const float4*)(xr1 + f);
            s0 += (double)v0.x * (double)scf[f]   + (double)v0.y * (double)scf[f+1]
                + (double)v0.z * (double)scf[f+2] + (double)v0.w * (double)scf[f+3];
            s1 += (double)v1.x * (double)scf[f]   + (double)v1.y * (double)scf[f+1]
                + (double)v1.z * (double)scf[f+2] + (double)v1.w * (double)scf[f+3];
        }
        ls0 = s0 * inv + (double)mask[t * NN + n0];
        ls1 = s1 * inv + (double)mask[t * NN + n1];
    }

    // per-wave top-64 of its 128 elems; elem e of lane: n = e*1024 + w*64 + lane
    for (int r = 0; r < 64; ++r) {
        double bv; int bi;
        if (ls0 > ls1 || (ls0 == ls1)) { bv = ls0; bi = (w << 6) + lane; }
        else                           { bv = ls1; bi = 1024 + (w << 6) + lane; }
#pragma unroll
        for (int off = 1; off < 64; off <<= 1) {
            double ov = __shfl_xor(bv, off);
            int    oi = __shfl_xor(bi, off);
            if (ov > bv || (ov == bv && oi < bi)) { bv = ov; bi = oi; }
        }
        if (lane == 0) { sk[(w << 6) + r] = bv; si[(w << 6) + r] = bi; }
        if ((bi & 63) == lane) {
            if (bi < 1024) ls0 = -INFINITY; else ls1 = -INFINITY;
        }
    }
    __syncthreads();

    // bitonic sort 1024 candidates, best-first (desc, idx asc)
    for (int k = 2; k <= 1024; k <<= 1) {
        for (int jj = k >> 1; jj > 0; jj >>= 1) {
            const int i = tid, l = i ^ jj;
            if (l > i) {
                const double a = sk[i], b2 = sk[l];
                const int ai = si[i], bi2 = si[l];
                const bool ib = (a > b2) || (a == b2 && ai < bi2);
                const bool keep = ((i & k) == 0) ? ib : !ib;
                if (!keep) {
                    sk[i] = b2; sk[l] = a;
                    si[i] = bi2; si[l] = ai;
                }
            }
            __syncthreads();
        }
    }

    if (tid < 64) {
        tkidx[t * 64 + tid] = si[tid];
        tkval[t * 64 + tid] = tanhf((float)sk[tid]);
    }
}

// ---------------------------------------------------------------------------
// K_B (qchain + fused Wz): 64 blocks x 256.  Per column j:
// gate_pre[i] = (W_m @ z_j)[i] + (U_m @ q)[i] + b_m[i][j], computed in ONE
// shuffle reduce (thread carries both U-row and W-row 16-f slices).
// z_j[f] = X[t][idx_j][f] * tanh(v_j) built in LDS per t (scalar idx/val).
// ---------------------------------------------------------------------------
__global__ __launch_bounds__(256) void qchain_kernel(
    const float* __restrict__ Q0,
    const float* __restrict__ Uu, const float* __restrict__ Ur,
    const float* __restrict__ Uh,
    const float* __restrict__ Wu, const float* __restrict__ Wr,
    const float* __restrict__ Wh,
    const float* __restrict__ bu, const float* __restrict__ br,
    const float* __restrict__ bh,
    const int* __restrict__ tkidx, const float* __restrict__ tkval,
    const float* __restrict__ X, float* __restrict__ Qseq)
{
    const int j = blockIdx.x, tid = threadIdx.x;
    const int w = tid >> 6, l = tid & 63;
    const int i = (w << 4) + (l & 15);
    const int fq = l >> 4, fb = fq << 4;

    float uu[16], ur[16], uh[16], wu[16], wr[16], wh[16];
#pragma unroll
    for (int e = 0; e < 16; e += 4) {
        float4 a = *(const float4*)(Uu + i * 64 + fb + e);
        uu[e] = a.x; uu[e+1] = a.y; uu[e+2] = a.z; uu[e+3] = a.w;
        float4 c = *(const float4*)(Ur + i * 64 + fb + e);
        ur[e] = c.x; ur[e+1] = c.y; ur[e+2] = c.z; ur[e+3] = c.w;
        float4 d = *(const float4*)(Uh + i * 64 + fb + e);
        uh[e] = d.x; uh[e+1] = d.y; uh[e+2] = d.z; uh[e+3] = d.w;
        float4 p = *(const float4*)(Wu + i * 64 + fb + e);
        wu[e] = p.x; wu[e+1] = p.y; wu[e+2] = p.z; wu[e+3] = p.w;
        float4 s = *(const float4*)(Wr + i * 64 + fb + e);
        wr[e] = s.x; wr[e+1] = s.y; wr[e+2] = s.z; wr[e+3] = s.w;
        float4 g = *(const float4*)(Wh + i * 64 + fb + e);
        wh[e] = g.x; wh[e+1] = g.y; wh[e+2] = g.z; wh[e+3] = g.w;
    }
    const float bui = bu[i * 64 + j];
    const float bri = br[i * 64 + j];
    const float bhi = bh[i * 64 + j];

    __shared__ __align__(16) float q[64];
    __shared__ __align__(16) float rr[64];
    __shared__ __align__(16) float zsh[64];
    if (tid < 64) q[tid] = Q0[tid * 64 + j];
    __syncthreads();

    for (int t = 0; t < TT; ++t) {
        const int   idx = tkidx[t * 64 + j];
        const float th  = tkval[t * 64 + j];
        if (tid < 64) zsh[tid] = X[((size_t)t * NN + idx) * FF + tid] * th;
        __syncthreads();

        float q16[16], z16[16];
#pragma unroll
        for (int e = 0; e < 16; e += 4) {
            f32x4 v = *(const f32x4*)(&q[fb + e]);
            q16[e] = v[0]; q16[e+1] = v[1]; q16[e+2] = v[2]; q16[e+3] = v[3];
            f32x4 z = *(const f32x4*)(&zsh[fb + e]);
            z16[e] = z[0]; z16[e+1] = z[1]; z16[e+2] = z[2]; z16[e+3] = z[3];
        }
        float su = 0.f, sr = 0.f, swh = 0.f;
#pragma unroll
        for (int e = 0; e < 16; ++e) {
            su  += uu[e] * q16[e] + wu[e] * z16[e];
            sr  += ur[e] * q16[e] + wr[e] * z16[e];
            swh += wh[e] * z16[e];
        }
        su  += __shfl_xor(su, 16);  su  += __shfl_xor(su, 32);
        sr  += __shfl_xor(sr, 16);  sr  += __shfl_xor(sr, 32);
        swh += __shfl_xor(swh, 16); swh += __shfl_xor(swh, 32);
        const float u_ = 1.f / (1.f + expf(-(su + bui)));
        const float r_ = 1.f / (1.f + expf(-(sr + bri)));
        if (fq == 0) rr[i] = r_;
        __syncthreads();
        float sh = 0.f;
#pragma unroll
        for (int e = 0; e < 16; e += 4) {
            f32x4 v = *(const f32x4*)(&rr[fb + e]);
            sh += uh[e]   * (v[0] * q16[e]);
            sh += uh[e+1] * (v[1] * q16[e+1]);
            sh += uh[e+2] * (v[2] * q16[e+2]);
            sh += uh[e+3] * (v[3] * q16[e+3]);
        }
        sh += __shfl_xor(sh, 16); sh += __shfl_xor(sh, 32);
        float hv = sh + swh + bhi;
        hv = hv > 0.f ? hv : 0.f;
        const float qi = q[i];
        const float qn = (1.f - u_) * qi + u_ * hv;
        __syncthreads();
        if (fq == 0) {
            q[i] = qn;
            Qseq[(size_t)t * 4096 + i * 64 + j] = qn;
        }
        __syncthreads();
    }
}

// ---------------------------------------------------------------------------
// K_C: Ytr[t][j][n] = bf16( sum_f X[t][n][f] * Qseq[t][f][j] )
// LDS transpose -> 16B contiguous global stores.  (R14-proven)
// ---------------------------------------------------------------------------
__global__ __launch_bounds__(256) void y_kernel(
    const float* __restrict__ X, const float* __restrict__ Qseq,
    unsigned short* __restrict__ Ytr)
{
    const int t = blockIdx.y, tid = threadIdx.x;
    const int n0 = blockIdx.x * 256;
    const int n = n0 + tid;
    __shared__ __align__(16) float Qs[4096];
    __shared__ __align__(16) unsigned short Ys[64][264];
    for (int c = tid; c < 4096; c += 256) Qs[c] = Qseq[(size_t)t * 4096 + c];
    __syncthreads();

    const float* xr = X + ((size_t)t * NN + n) * FF;
    float y[64];
#pragma unroll
    for (int jj = 0; jj < 64; ++jj) y[jj] = 0.f;
    for (int f4 = 0; f4 < 64; f4 += 4) {
        float4 xv = *(const float4*)(xr + f4);
        float xa[4] = {xv.x, xv.y, xv.z, xv.w};
#pragma unroll
        for (int ff = 0; ff < 4; ++ff) {
            const float xf = xa[ff];
            const float* qr = &Qs[(f4 + ff) << 6];
#pragma unroll
            for (int jj = 0; jj < 64; jj += 4) {
                f32x4 qv = *(const f32x4*)(qr + jj);
                y[jj]   += xf * qv[0];
                y[jj+1] += xf * qv[1];
                y[jj+2] += xf * qv[2];
                y[jj+3] += xf * qv[3];
            }
        }
    }
#pragma unroll
    for (int jj = 0; jj < 64; ++jj) Ys[jj][tid] = f2bf(y[jj]);
    __syncthreads();

    const int j = tid >> 2, nc = (tid & 3) << 6;
    unsigned short* yo = Ytr + (size_t)t * FF * NN + (size_t)j * NN + n0 + nc;
#pragma unroll
    for (int c = 0; c < 8; ++c)
        *(u16x8*)(yo + c * 8) = *(const u16x8*)(&Ys[j][nc + c * 8]);
}

// ---------------------------------------------------------------------------
// K_D: out[t] = relu(A[t] @ Y[t]).  R10 gemm (measured 112us @ 4.6 TB/s).
// ---------------------------------------------------------------------------
__global__ __launch_bounds__(256, 4) void gemm_kernel(
    const float* __restrict__ A, const unsigned short* __restrict__ Ytr,
    float* __restrict__ out)
{
    __shared__ __align__(16) unsigned char Abuf[16384];  // f32 [64 r][256B]
    __shared__ __align__(16) unsigned char Bbuf[8192];   // bf16 [64 j][128B]
    const int tid = threadIdx.x;
    const int bid = blockIdx.x;
    const int xcd = bid & 7, li = bid >> 3;          // 8 XCDs x 128 blocks
    const int t = (xcd << 2) + (li >> 5);            // 4 timesteps per XCD
    const int m0 = (li & 31) * 64;
    const int lane = tid & 63, w = tid >> 6;
    const int lr = lane & 15, lq = lane >> 4;

    const float* Ap = A + (size_t)t * NN * NN + (size_t)m0 * NN;
    const unsigned short* Yp = Ytr + (size_t)t * FF * NN;

    f32x4 acc[4];
#pragma unroll
    for (int nt = 0; nt < 4; ++nt) acc[nt] = (f32x4){0.f, 0.f, 0.f, 0.f};

    for (int kt = 0; kt < 32; ++kt) {
        const int kk = kt << 6;
#pragma unroll
        for (int q = 0; q < 4; ++q) {
            const int row = (w << 4) + (q << 2) + lq;
            const float* g = Ap + (size_t)row * NN + kk + ((lr ^ (row & 7)) << 2);
            __builtin_amdgcn_global_load_lds(
                (const __attribute__((address_space(1))) void*)g,
                (__attribute__((address_space(3))) void*)
                    (&Abuf[((w << 4) + (q << 2)) << 8]), 16, 0, 0);
        }
#pragma unroll
        for (int q = 0; q < 2; ++q) {
            const int j = (w << 4) + (q << 3) + (lane >> 3);
            const unsigned short* g = Yp + (size_t)j * NN + kk
                                    + (((lane & 7) ^ (j & 7)) << 3);
            __builtin_amdgcn_global_load_lds(
                (const __attribute__((address_space(1))) void*)g,
                (__attribute__((address_space(3))) void*)
                    (&Bbuf[((w << 4) + (q << 3)) << 7]), 16, 0, 0);
        }
        __syncthreads();
#pragma unroll
        for (int ks = 0; ks < 2; ++ks) {
            const int r = (w << 4) + lr;
            const int c0 = ((ks << 3) + (lq << 1)) ^ (lr & 7);
            const int c1 = ((ks << 3) + (lq << 1) + 1) ^ (lr & 7);
            const f32x4 a0 = *(const f32x4*)(&Abuf[(r << 8) + (c0 << 4)]);
            const f32x4 a1 = *(const f32x4*)(&Abuf[(r << 8) + (c1 << 4)]);
            bf16x8 af;
            af[0] = (__bf16)a0[0]; af[1] = (__bf16)a0[1];
            af[2] = (__bf16)a0[2]; af[3] = (__bf16)a0[3];
            af[4] = (__bf16)a1[0]; af[5] = (__bf16)a1[1];
            af[6] = (__bf16)a1[2]; af[7] = (__bf16)a1[3];
#pragma unroll
            for (int nt = 0; nt < 4; ++nt) {
                const int j = (nt << 4) + lr;
                const int x = ((ks << 2) + lq) ^ (j & 7);
                const bf16x8 bf = *(const bf16x8*)(&Bbuf[(j << 7) + (x << 4)]);
                acc[nt] = __builtin_amdgcn_mfma_f32_16x16x32_bf16(
                    af, bf, acc[nt], 0, 0, 0);
            }
        }
        __syncthreads();
    }

#pragma unroll
    for (int nt = 0; nt < 4; ++nt) {
        const int row0 = m0 + (w << 4) + (lq << 2);
        const int col = (nt << 4) + lr;
#pragma unroll
        for (int rg = 0; rg < 4; ++rg) {
            const float v = acc[nt][rg];
            out[((size_t)t * NN + (row0 + rg)) * FF + col] = v > 0.f ? v : 0.f;
        }
    }
}

// ---------------------------------------------------------------------------
extern "C" void kernel_launch(void* const* d_in, const int* in_sizes, int n_in,
                              void* d_out, int out_size, void* d_ws, size_t ws_size,
                              hipStream_t stream) {
    const float* A      = (const float*)d_in[0];
    const float* X      = (const float*)d_in[1];
    const float* mask   = (const float*)d_in[2];
    const float* Q0     = (const float*)d_in[3];
    const float* scorer = (const float*)d_in[4];
    const float* Wu     = (const float*)d_in[5];
    const float* Uu     = (const float*)d_in[6];
    const float* bu     = (const float*)d_in[7];
    const float* Wr     = (const float*)d_in[8];
    const float* Ur     = (const float*)d_in[9];
    const float* br     = (const float*)d_in[10];
    const float* Wh     = (const float*)d_in[11];
    const float* Uh     = (const float*)d_in[12];
    const float* bh     = (const float*)d_in[13];
    float* out = (float*)d_out;

    float* ws    = (float*)d_ws;
    int*   tkidx = (int*)ws;                       // [T][64]
    float* tkval = ws + 4096;                      // [T][64]
    float* Qseq  = ws + 524288;                    // [T][64][64]
    unsigned short* Ytr = (unsigned short*)(ws + 655360);  // [T][64][2048] bf16

    topk_kernel<<<TT, 1024, 0, stream>>>(X, mask, scorer, tkidx, tkval);
    qchain_kernel<<<FF, 256, 0, stream>>>(Q0, Uu, Ur, Uh, Wu, Wr, Wh,
                                          bu, br, bh, tkidx, tkval, X, Qseq);
    y_kernel<<<dim3(NN / 256, TT), 256, 0, stream>>>(X, Qseq, Ytr);
    gemm_kernel<<<1024, 256, 0, stream>>>(A, Ytr, out);
}

// Round 17
// 253.076 us; speedup vs baseline: 1.8395x; 1.1836x over previous
//
#include <hip/hip_runtime.h>
#include <hip/hip_bf16.h>
#include <math.h>

#define TT 32
#define NN 2048
#define FF 64

typedef float f32x4 __attribute__((ext_vector_type(4)));
typedef __bf16 bf16x8 __attribute__((ext_vector_type(8)));
typedef unsigned short u16x8 __attribute__((ext_vector_type(8)));

__device__ __forceinline__ unsigned short f2bf(float f) {
    __bf16 h = (__bf16)f;
    return __builtin_bit_cast(unsigned short, h);
}

// ---------------------------------------------------------------------------
// K_S: wide scoring kernel. grid (8, 32) x 256.  Thread owns row n:
// scores[t][n] = fp64( X[t][n]@scorer / ||scorer|| + mask[t][n] ),
// and writes Xbf16[t][n][f] (B-operand for the y-MFMA kernel).
// ---------------------------------------------------------------------------
__global__ __launch_bounds__(256) void score_kernel(
    const float* __restrict__ X, const float* __restrict__ mask,
    const float* __restrict__ scorer,
    double* __restrict__ scores, unsigned short* __restrict__ Xbf)
{
    const int t = blockIdx.y, tid = threadIdx.x;
    const int n = blockIdx.x * 256 + tid;
    __shared__ float scf[64];
    if (tid < 64) scf[tid] = scorer[tid];
    __syncthreads();

    double nrm = 0.0;
#pragma unroll
    for (int f = 0; f < 64; ++f) nrm += (double)scf[f] * (double)scf[f];
    const double inv = 1.0 / sqrt(nrm);

    const float* xr = X + ((size_t)t * NN + n) * FF;
    unsigned short* xo = Xbf + ((size_t)t * NN + n) * FF;
    double s = 0.0;
#pragma unroll
    for (int f = 0; f < 64; f += 4) {
        float4 v = *(const float4*)(xr + f);
        s += (double)v.x * (double)scf[f]   + (double)v.y * (double)scf[f+1]
           + (double)v.z * (double)scf[f+2] + (double)v.w * (double)scf[f+3];
        ushort4 pk = make_ushort4(f2bf(v.x), f2bf(v.y), f2bf(v.z), f2bf(v.w));
        *(ushort4*)(xo + f) = pk;
    }
    scores[t * NN + n] = s * inv + (double)mask[t * NN + n];
}

// ---------------------------------------------------------------------------
// K_A select: 32 blocks x 1024.  Loads precomputed fp64 scores; per-wave
// top-64-of-128 extraction + 1024-candidate bitonic (R16-proven code).
// Writes (idx, tanh(val)).
// ---------------------------------------------------------------------------
__global__ __launch_bounds__(1024) void select_kernel(
    const double* __restrict__ scores,
    int* __restrict__ tkidx, float* __restrict__ tkval)
{
    const int t = blockIdx.x, tid = threadIdx.x;
    const int lane = tid & 63, w = tid >> 6;
    __shared__ double sk[1024];
    __shared__ int    si[1024];

    double ls0 = scores[t * NN + tid];
    double ls1 = scores[t * NN + 1024 + tid];

    for (int r = 0; r < 64; ++r) {
        double bv; int bi;
        if (ls0 > ls1 || (ls0 == ls1)) { bv = ls0; bi = (w << 6) + lane; }
        else                           { bv = ls1; bi = 1024 + (w << 6) + lane; }
#pragma unroll
        for (int off = 1; off < 64; off <<= 1) {
            double ov = __shfl_xor(bv, off);
            int    oi = __shfl_xor(bi, off);
            if (ov > bv || (ov == bv && oi < bi)) { bv = ov; bi = oi; }
        }
        if (lane == 0) { sk[(w << 6) + r] = bv; si[(w << 6) + r] = bi; }
        if ((bi & 63) == lane) {
            if (bi < 1024) ls0 = -INFINITY; else ls1 = -INFINITY;
        }
    }
    __syncthreads();

    for (int k = 2; k <= 1024; k <<= 1) {
        for (int jj = k >> 1; jj > 0; jj >>= 1) {
            const int i = tid, l = i ^ jj;
            if (l > i) {
                const double a = sk[i], b2 = sk[l];
                const int ai = si[i], bi2 = si[l];
                const bool ib = (a > b2) || (a == b2 && ai < bi2);
                const bool keep = ((i & k) == 0) ? ib : !ib;
                if (!keep) {
                    sk[i] = b2; sk[l] = a;
                    si[i] = bi2; si[l] = ai;
                }
            }
            __syncthreads();
        }
    }

    if (tid < 64) {
        tkidx[t * 64 + tid] = si[tid];
        tkval[t * 64 + tid] = tanhf((float)sk[tid]);
    }
}

// ---------------------------------------------------------------------------
// K_B qchain v5: 64 blocks x 256.  Prefetch all 32 z-rows into LDS; then
// precompute ALL W_m@z_t dot-products (parallel, outside serial loop);
// serial 32-step loop touches only LDS + shuffles.  Writes Qtr[t][j][f] bf16.
// ---------------------------------------------------------------------------
__global__ __launch_bounds__(256) void qchain_kernel(
    const float* __restrict__ Q0,
    const float* __restrict__ Uu, const float* __restrict__ Ur,
    const float* __restrict__ Uh,
    const float* __restrict__ Wu, const float* __restrict__ Wr,
    const float* __restrict__ Wh,
    const float* __restrict__ bu, const float* __restrict__ br,
    const float* __restrict__ bh,
    const int* __restrict__ tkidx, const float* __restrict__ tkval,
    const float* __restrict__ X, unsigned short* __restrict__ Qtr)
{
    const int j = blockIdx.x, tid = threadIdx.x;
    const int w = tid >> 6, l = tid & 63;
    const int i = (w << 4) + (l & 15);
    const int fq = l >> 4, fb = fq << 4;

    __shared__ __align__(16) float zsh[TT][64];   // 8 KB
    __shared__ __align__(16) float wzl[3 * TT * 64]; // 24 KB
    __shared__ __align__(16) float q[64];
    __shared__ __align__(16) float rr[64];

    // prefetch z rows: thread -> t = tid>>3, 8-float slice (tid&7)*8
    {
        const int tt = tid >> 3, p8 = (tid & 7) << 3;
        const int idxt = tkidx[tt * 64 + j];
        const float th = tkval[tt * 64 + j];
        const float* xr = X + ((size_t)tt * NN + idxt) * FF + p8;
        float4 v0 = *(const float4*)(xr);
        float4 v1 = *(const float4*)(xr + 4);
        zsh[tt][p8]     = v0.x * th; zsh[tt][p8 + 1] = v0.y * th;
        zsh[tt][p8 + 2] = v0.z * th; zsh[tt][p8 + 3] = v0.w * th;
        zsh[tt][p8 + 4] = v1.x * th; zsh[tt][p8 + 5] = v1.y * th;
        zsh[tt][p8 + 6] = v1.z * th; zsh[tt][p8 + 7] = v1.w * th;
    }

    float uu[16], ur[16], uh[16], wu[16], wr[16], wh[16];
#pragma unroll
    for (int e = 0; e < 16; e += 4) {
        float4 a = *(const float4*)(Uu + i * 64 + fb + e);
        uu[e] = a.x; uu[e+1] = a.y; uu[e+2] = a.z; uu[e+3] = a.w;
        float4 c = *(const float4*)(Ur + i * 64 + fb + e);
        ur[e] = c.x; ur[e+1] = c.y; ur[e+2] = c.z; ur[e+3] = c.w;
        float4 d = *(const float4*)(Uh + i * 64 + fb + e);
        uh[e] = d.x; uh[e+1] = d.y; uh[e+2] = d.z; uh[e+3] = d.w;
        float4 p = *(const float4*)(Wu + i * 64 + fb + e);
        wu[e] = p.x; wu[e+1] = p.y; wu[e+2] = p.z; wu[e+3] = p.w;
        float4 s = *(const float4*)(Wr + i * 64 + fb + e);
        wr[e] = s.x; wr[e+1] = s.y; wr[e+2] = s.z; wr[e+3] = s.w;
        float4 g = *(const float4*)(Wh + i * 64 + fb + e);
        wh[e] = g.x; wh[e+1] = g.y; wh[e+2] = g.z; wh[e+3] = g.w;
    }
    const float bui = bu[i * 64 + j];
    const float bri = br[i * 64 + j];
    const float bhi = bh[i * 64 + j];
    if (tid < 64) q[tid] = Q0[tid * 64 + j];
    __syncthreads();

    // precompute W_m @ z_t for all t (parallel)
    for (int t = 0; t < TT; ++t) {
        float z16[16];
#pragma unroll
        for (int e = 0; e < 16; e += 4) {
            f32x4 z = *(const f32x4*)(&zsh[t][fb + e]);
            z16[e] = z[0]; z16[e+1] = z[1]; z16[e+2] = z[2]; z16[e+3] = z[3];
        }
        float pu = 0.f, pr = 0.f, ph = 0.f;
#pragma unroll
        for (int e = 0; e < 16; ++e) {
            pu += wu[e] * z16[e];
            pr += wr[e] * z16[e];
            ph += wh[e] * z16[e];
        }
        pu += __shfl_xor(pu, 16); pu += __shfl_xor(pu, 32);
        pr += __shfl_xor(pr, 16); pr += __shfl_xor(pr, 32);
        ph += __shfl_xor(ph, 16); ph += __shfl_xor(ph, 32);
        if (fq == 0) {
            wzl[(0 * TT + t) * 64 + i] = pu;
            wzl[(1 * TT + t) * 64 + i] = pr;
            wzl[(2 * TT + t) * 64 + i] = ph;
        }
    }
    __syncthreads();

    // serial recurrence
    for (int t = 0; t < TT; ++t) {
        float q16[16];
#pragma unroll
        for (int e = 0; e < 16; e += 4) {
            f32x4 v = *(const f32x4*)(&q[fb + e]);
            q16[e] = v[0]; q16[e+1] = v[1]; q16[e+2] = v[2]; q16[e+3] = v[3];
        }
        float su = 0.f, sr = 0.f;
#pragma unroll
        for (int e = 0; e < 16; ++e) { su += uu[e] * q16[e]; sr += ur[e] * q16[e]; }
        su += __shfl_xor(su, 16); su += __shfl_xor(su, 32);
        sr += __shfl_xor(sr, 16); sr += __shfl_xor(sr, 32);
        const float u_ = 1.f / (1.f + expf(-(su + wzl[(0 * TT + t) * 64 + i] + bui)));
        const float r_ = 1.f / (1.f + expf(-(sr + wzl[(1 * TT + t) * 64 + i] + bri)));
        if (fq == 0) rr[i] = r_;
        __syncthreads();
        float sh = 0.f;
#pragma unroll
        for (int e = 0; e < 16; e += 4) {
            f32x4 v = *(const f32x4*)(&rr[fb + e]);
            sh += uh[e]   * (v[0] * q16[e]);
            sh += uh[e+1] * (v[1] * q16[e+1]);
            sh += uh[e+2] * (v[2] * q16[e+2]);
            sh += uh[e+3] * (v[3] * q16[e+3]);
        }
        sh += __shfl_xor(sh, 16); sh += __shfl_xor(sh, 32);
        float hv = sh + wzl[(2 * TT + t) * 64 + i] + bhi;
        hv = hv > 0.f ? hv : 0.f;
        const float qi = q[i];
        const float qn = (1.f - u_) * qi + u_ * hv;
        __syncthreads();
        if (fq == 0) {
            q[i] = qn;
            // Qtr[t][j][f=i] bf16
            Qtr[(size_t)t * 4096 + j * 64 + i] = f2bf(qn);
        }
        __syncthreads();
    }
}

// ---------------------------------------------------------------------------
// K_C y-MFMA: Ytr[t][j][n] = bf16( sum_f Qtr[t][j][f] * Xbf[t][n][f] ).
// grid (8 n-tiles, 32 t) x 256.  A = Qtr staged in LDS (gemm-Bbuf-style
// swizzle, verbatim); B = Xbf rows direct from L2.  32 MFMA/wave.
// ---------------------------------------------------------------------------
__global__ __launch_bounds__(256) void ymfma_kernel(
    const unsigned short* __restrict__ Xbf, const unsigned short* __restrict__ Qtr,
    unsigned short* __restrict__ Ytr)
{
    __shared__ __align__(16) unsigned char Qb[8192];   // bf16 [64 j][128B]
    const int t = blockIdx.y, tid = threadIdx.x;
    const int n0 = blockIdx.x * 256;
    const int lane = tid & 63, w = tid >> 6;
    const int lr = lane & 15, lq = lane >> 4;

    const unsigned short* Qp = Qtr + (size_t)t * 4096;
    // stage Qtr[t] (8 KB): same pattern as gemm B-staging
#pragma unroll
    for (int q2 = 0; q2 < 2; ++q2) {
        const int j = (w << 4) + (q2 << 3) + (lane >> 3);
        const unsigned short* g = Qp + (size_t)j * 64 + (((lane & 7) ^ (j & 7)) << 3);
        __builtin_amdgcn_global_load_lds(
            (const __attribute__((address_space(1))) void*)g,
            (__attribute__((address_space(3))) void*)
                (&Qb[((w << 4) + (q2 << 3)) << 7]), 16, 0, 0);
    }
    __syncthreads();

    f32x4 acc[4][4];
#pragma unroll
    for (int jt = 0; jt < 4; ++jt)
#pragma unroll
        for (int nt = 0; nt < 4; ++nt) acc[jt][nt] = (f32x4){0.f, 0.f, 0.f, 0.f};

#pragma unroll
    for (int ks = 0; ks < 2; ++ks) {
        bf16x8 af[4], bf[4];
#pragma unroll
        for (int jt = 0; jt < 4; ++jt) {
            const int j = (jt << 4) + lr;
            const int x = ((ks << 2) + lq) ^ (j & 7);
            af[jt] = *(const bf16x8*)(&Qb[(j << 7) + (x << 4)]);
        }
#pragma unroll
        for (int nt = 0; nt < 4; ++nt) {
            const int n = n0 + (w << 6) + (nt << 4) + lr;
            bf[nt] = __builtin_bit_cast(bf16x8,
                *(const uint4*)(Xbf + ((size_t)t * NN + n) * FF + (ks << 5) + (lq << 3)));
        }
#pragma unroll
        for (int jt = 0; jt < 4; ++jt)
#pragma unroll
            for (int nt = 0; nt < 4; ++nt)
                acc[jt][nt] = __builtin_amdgcn_mfma_f32_16x16x32_bf16(
                    af[jt], bf[nt], acc[jt][nt], 0, 0, 0);
    }

    // store: D row = j = jt*16 + lq*4 + rg, col = n = n0 + w*64 + nt*16 + lr
#pragma unroll
    for (int jt = 0; jt < 4; ++jt)
#pragma unroll
        for (int nt = 0; nt < 4; ++nt) {
            const int nn = n0 + (w << 6) + (nt << 4) + lr;
#pragma unroll
            for (int rg = 0; rg < 4; ++rg) {
                const int j = (jt << 4) + (lq << 2) + rg;
                Ytr[(size_t)t * FF * NN + (size_t)j * NN + nn] = f2bf(acc[jt][nt][rg]);
            }
        }
}

// ---------------------------------------------------------------------------
// K_D: out[t] = relu(A[t] @ Y[t]).  R10 gemm (measured 112us @ 4.6 TB/s).
// ---------------------------------------------------------------------------
__global__ __launch_bounds__(256, 4) void gemm_kernel(
    const float* __restrict__ A, const unsigned short* __restrict__ Ytr,
    float* __restrict__ out)
{
    __shared__ __align__(16) unsigned char Abuf[16384];  // f32 [64 r][256B]
    __shared__ __align__(16) unsigned char Bbuf[8192];   // bf16 [64 j][128B]
    const int tid = threadIdx.x;
    const int bid = blockIdx.x;
    const int xcd = bid & 7, li = bid >> 3;          // 8 XCDs x 128 blocks
    const int t = (xcd << 2) + (li >> 5);            // 4 timesteps per XCD
    const int m0 = (li & 31) * 64;
    const int lane = tid & 63, w = tid >> 6;
    const int lr = lane & 15, lq = lane >> 4;

    const float* Ap = A + (size_t)t * NN * NN + (size_t)m0 * NN;
    const unsigned short* Yp = Ytr + (size_t)t * FF * NN;

    f32x4 acc[4];
#pragma unroll
    for (int nt = 0; nt < 4; ++nt) acc[nt] = (f32x4){0.f, 0.f, 0.f, 0.f};

    for (int kt = 0; kt < 32; ++kt) {
        const int kk = kt << 6;
#pragma unroll
        for (int q = 0; q < 4; ++q) {
            const int row = (w << 4) + (q << 2) + lq;
            const float* g = Ap + (size_t)row * NN + kk + ((lr ^ (row & 7)) << 2);
            __builtin_amdgcn_global_load_lds(
                (const __attribute__((address_space(1))) void*)g,
                (__attribute__((address_space(3))) void*)
                    (&Abuf[((w << 4) + (q << 2)) << 8]), 16, 0, 0);
        }
#pragma unroll
        for (int q = 0; q < 2; ++q) {
            const int j = (w << 4) + (q << 3) + (lane >> 3);
            const unsigned short* g = Yp + (size_t)j * NN + kk
                                    + (((lane & 7) ^ (j & 7)) << 3);
            __builtin_amdgcn_global_load_lds(
                (const __attribute__((address_space(1))) void*)g,
                (__attribute__((address_space(3))) void*)
                    (&Bbuf[((w << 4) + (q << 3)) << 7]), 16, 0, 0);
        }
        __syncthreads();
#pragma unroll
        for (int ks = 0; ks < 2; ++ks) {
            const int r = (w << 4) + lr;
            const int c0 = ((ks << 3) + (lq << 1)) ^ (lr & 7);
            const int c1 = ((ks << 3) + (lq << 1) + 1) ^ (lr & 7);
            const f32x4 a0 = *(const f32x4*)(&Abuf[(r << 8) + (c0 << 4)]);
            const f32x4 a1 = *(const f32x4*)(&Abuf[(r << 8) + (c1 << 4)]);
            bf16x8 af;
            af[0] = (__bf16)a0[0]; af[1] = (__bf16)a0[1];
            af[2] = (__bf16)a0[2]; af[3] = (__bf16)a0[3];
            af[4] = (__bf16)a1[0]; af[5] = (__bf16)a1[1];
            af[6] = (__bf16)a1[2]; af[7] = (__bf16)a1[3];
#pragma unroll
            for (int nt = 0; nt < 4; ++nt) {
                const int j = (nt << 4) + lr;
                const int x = ((ks << 2) + lq) ^ (j & 7);
                const bf16x8 bf = *(const bf16x8*)(&Bbuf[(j << 7) + (x << 4)]);
                acc[nt] = __builtin_amdgcn_mfma_f32_16x16x32_bf16(
                    af, bf, acc[nt], 0, 0, 0);
            }
        }
        __syncthreads();
    }

#pragma unroll
    for (int nt = 0; nt < 4; ++nt) {
        const int row0 = m0 + (w << 4) + (lq << 2);
        const int col = (nt << 4) + lr;
#pragma unroll
        for (int rg = 0; rg < 4; ++rg) {
            const float v = acc[nt][rg];
            out[((size_t)t * NN + (row0 + rg)) * FF + col] = v > 0.f ? v : 0.f;
        }
    }
}

// ---------------------------------------------------------------------------
extern "C" void kernel_launch(void* const* d_in, const int* in_sizes, int n_in,
                              void* d_out, int out_size, void* d_ws, size_t ws_size,
                              hipStream_t stream) {
    const float* A      = (const float*)d_in[0];
    const float* X      = (const float*)d_in[1];
    const float* mask   = (const float*)d_in[2];
    const float* Q0     = (const float*)d_in[3];
    const float* scorer = (const float*)d_in[4];
    const float* Wu     = (const float*)d_in[5];
    const float* Uu     = (const float*)d_in[6];
    const float* bu     = (const float*)d_in[7];
    const float* Wr     = (const float*)d_in[8];
    const float* Ur     = (const float*)d_in[9];
    const float* br     = (const float*)d_in[10];
    const float* Wh     = (const float*)d_in[11];
    const float* Uh     = (const float*)d_in[12];
    const float* bh     = (const float*)d_in[13];
    float* out = (float*)d_out;

    float* ws = (float*)d_ws;
    double* scores        = (double*)ws;                          // [32][2048] fp64
    int*    tkidx         = (int*)(ws + 131072);                  // [32][64]
    float*  tkval         = ws + 133120;                          // [32][64]
    unsigned short* Qtr   = (unsigned short*)(ws + 135168);       // [32][64][64] bf16
    unsigned short* Xbf   = (unsigned short*)(ws + 200704);       // [32][2048][64] bf16
    unsigned short* Ytr   = (unsigned short*)(ws + 2297856);      // [32][64][2048] bf16

    score_kernel<<<dim3(8, TT), 256, 0, stream>>>(X, mask, scorer, scores, Xbf);
    select_kernel<<<TT, 1024, 0, stream>>>(scores, tkidx, tkval);
    qchain_kernel<<<FF, 256, 0, stream>>>(Q0, Uu, Ur, Uh, Wu, Wr, Wh,
                                          bu, br, bh, tkidx, tkval, X, Qtr);
    ymfma_kernel<<<dim3(8, TT), 256, 0, stream>>>(Xbf, Qtr, Ytr);
    gemm_kernel<<<1024, 256, 0, stream>>>(A, Ytr, out);
}